// Round 1
// baseline (145.298 us; speedup 1.0000x reference)
//
#include <hip/hip_runtime.h>
#include <hip/hip_bf16.h>
#include <math.h>

// Problem constants (reference: VOCAB=50257, E=64, D=16, DK=32, B=32, S=2048)
#define EDIM 64
#define DDOM 16
#define DKDIM 32

// ---------------------------------------------------------------------------
// Pre-kernel: detect how the harness materialized the bool `membership` array.
// Scans the first 4096 bytes (guaranteed in-bounds: >= 804112 elements >= 1 B each).
//   bit0 set -> bf16 (bytes 0x80 / 0x3F present)
//   bit1 set -> uint8 (a value 1 at a byte offset not divisible by 4)
//   0        -> int32 (bool widened to 0/1 int32: bytes are [v,0,0,0])
// ---------------------------------------------------------------------------
__global__ void detect_mtype(const unsigned char* __restrict__ mem, int* __restrict__ flag) {
    __shared__ int s;
    if (threadIdx.x == 0) s = 0;   // d_ws is poisoned 0xAA; must init ourselves
    __syncthreads();
    int saw = 0;
    for (int p = threadIdx.x; p < 4096; p += 256) {
        unsigned char b = mem[p];
        if (b != 0 && b != 1) saw |= 1;         // bf16 signature bytes
        if (b == 1 && (p & 3) != 0) saw |= 2;   // uint8 signature
    }
    if (saw) atomicOr(&s, saw);
    __syncthreads();
    if (threadIdx.x == 0) flag[0] = s;
}

// ---------------------------------------------------------------------------
// Main kernel: one 64-lane wave per token. Lane e owns h[e] and out[e].
// Active-domain skip: mask bits gathered via __ballot, loop is wave-uniform.
// ---------------------------------------------------------------------------
__global__ __launch_bounds__(256) void domain_embed(
    const int*   __restrict__ x,
    const float* __restrict__ tab,
    const float* __restrict__ W1,   // [D][E][DK]
    const float* __restrict__ W2,   // [D][DK][E]
    const void*  __restrict__ memb,
    const int*   __restrict__ flag,
    float*       __restrict__ out,
    int ntok)
{
    const int lane = threadIdx.x & 63;
    const int wid  = (int)((blockIdx.x * (unsigned)blockDim.x + threadIdx.x) >> 6);
    if (wid >= ntok) return;

    const int token = x[wid];
    const float h = tab[token * EDIM + lane];

    const int mcode = flag[0];  // uniform across grid
    bool pred = false;
    if (lane < DDOM) {
        const int mi = token * DDOM + lane;
        if (mcode & 1)      pred = ((const unsigned short*)memb)[mi] != 0;  // bf16 0.0/1.0
        else if (mcode & 2) pred = ((const unsigned char*) memb)[mi] != 0;  // uint8
        else                pred = ((const int*)           memb)[mi] != 0;  // int32
    }
    const unsigned long long mask = __ballot(pred) & 0xFFFFull;

    float corr = 0.f;
    if (mask) {
        const int k = lane & 31;
        #pragma unroll 1
        for (int d = 0; d < DDOM; ++d) {
            if (!((mask >> d) & 1ull)) continue;
            // step 1: u_k = sum_e h[e] * W1[d,e,k]   (lane role: k; h broadcast via readlane)
            const float* __restrict__ w1 = W1 + d * (EDIM * DKDIM);
            float u = 0.f;
            #pragma unroll
            for (int e = 0; e < EDIM; ++e) {
                u = fmaf(__shfl(h, e, 64), w1[e * DKDIM + k], u);
            }
            // exact GELU: x * 0.5 * (1 + erf(x/sqrt(2)))
            const float g = 0.5f * u * (1.f + erff(u * 0.70710678118654752f));
            // step 2: corr[e] += sum_k g[k] * W2[d,k,e]   (lane role: e; g broadcast)
            const float* __restrict__ w2 = W2 + d * (DKDIM * EDIM);
            #pragma unroll
            for (int kk = 0; kk < DKDIM; ++kk) {
                corr = fmaf(__shfl(g, kk, 64), w2[kk * EDIM + lane], corr);
            }
        }
    }
    out[wid * EDIM + lane] = h + 0.1f * corr;
}

extern "C" void kernel_launch(void* const* d_in, const int* in_sizes, int n_in,
                              void* d_out, int out_size, void* d_ws, size_t ws_size,
                              hipStream_t stream) {
    const int*   x    = (const int*)  d_in[0];
    const float* tab  = (const float*)d_in[1];
    const float* W1   = (const float*)d_in[2];
    const float* W2   = (const float*)d_in[3];
    const void*  memb =               d_in[4];
    float* out = (float*)d_out;
    int* flag = (int*)d_ws;

    const int ntok = in_sizes[0];              // B*S = 65536

    detect_mtype<<<1, 256, 0, stream>>>((const unsigned char*)memb, flag);

    const int blocks = (ntok * 64 + 255) / 256;  // one wave per token, 4 waves/block
    domain_embed<<<blocks, 256, 0, stream>>>(x, tab, W1, W2, memb, flag, out, ntok);
}

// Round 2
// 125.847 us; speedup vs baseline: 1.1546x; 1.1546x over previous
//
#include <hip/hip_runtime.h>
#include <hip/hip_bf16.h>
#include <math.h>

// Problem: VOCAB=50257, E=64, D=16, DK=32, B*S=65536, membership p=0.05
#define EDIM 64
#define DDOM 16
#define DKDIM 32
#define TPB 32          // tokens per block
#define NTHREADS 256

// Single fused kernel:
//  - per-block inline membership-dtype detection (first 4 KB, always in-bounds)
//  - block stages 32 tokens' h into LDS, builds active (token,domain) pair list
//    (expected 25.6 pairs/block at p=0.05 -> 20x FLOP skip)
//  - waves process pairs: step1 split over wave halves (32-FMA chains, not 64),
//    h broadcast via uniform-address ds_read_b128, W1/W2 loads independent for ILP
//  - gelu via 5th-order Taylor of Phi (|u|<0.02 w.p. ~1; erff fallback guarded)
//  - corr accumulated in LDS via atomicAdd (ds_add_f32), epilogue out = h + 0.1*corr
__global__ __launch_bounds__(256, 4) void domain_embed_fused(
    const int*   __restrict__ x,
    const float* __restrict__ tab,
    const float* __restrict__ W1,   // [D][E][DK]
    const float* __restrict__ W2,   // [D][DK][E]
    const unsigned char* __restrict__ memb,
    float*       __restrict__ out,
    int ntok)
{
    __shared__ float h_lds[TPB][EDIM];     // 8 KB
    __shared__ float corr[TPB][EDIM];      // 8 KB
    __shared__ int   tok_lds[TPB];
    __shared__ unsigned int mask_lds[TPB];
    __shared__ unsigned short pairs[TPB * DDOM];
    __shared__ int npairs;
    __shared__ int det_wave[4];

    const int thr  = threadIdx.x;
    const int lane = thr & 63;
    const int wid  = thr >> 6;
    const int tok0 = blockIdx.x * TPB;

    // ---- phase 1: token ids, zero corr, membership-dtype detection ----
    if (thr < TPB) {
        int t = tok0 + thr;
        tok_lds[thr] = (t < ntok) ? x[t] : 0;
    }
    #pragma unroll
    for (int i = 0; i < (TPB * EDIM) / NTHREADS; ++i)
        ((float*)corr)[thr + i * NTHREADS] = 0.f;
    if (thr == 0) npairs = 0;
    {
        // scan bytes [0,4096): membership >= 804112 elements >= 1 B each, in-bounds
        const uint4 v = ((const uint4*)memb)[thr];
        unsigned int w[4] = {v.x, v.y, v.z, v.w};
        bool sawbf = false, saw8 = false;
        #pragma unroll
        for (int dw = 0; dw < 4; ++dw) {
            #pragma unroll
            for (int b = 0; b < 4; ++b) {
                unsigned int byte = (w[dw] >> (8 * b)) & 0xFFu;
                if (byte > 1u) sawbf = true;            // bf16 signature (0x80/0x3F)
                if (byte == 1u && b != 0) saw8 = true;  // '1' at offset %4 != 0
            }
        }
        unsigned long long b1 = __ballot(sawbf);
        unsigned long long b2 = __ballot(saw8);
        if (lane == 0) det_wave[wid] = (b1 ? 1 : 0) | (b2 ? 2 : 0);
    }
    __syncthreads();

    const int mcode = det_wave[0] | det_wave[1] | det_wave[2] | det_wave[3];

    // ---- phase 2: gather h rows (coalesced 256 B/row), load membership ----
    #pragma unroll
    for (int pass = 0; pass < 2; ++pass) {
        int row = pass * 16 + (thr >> 4);
        int tokid = tok_lds[row];
        const float4 hv = ((const float4*)(tab + (size_t)tokid * EDIM))[thr & 15];
        ((float4*)&h_lds[row][0])[thr & 15] = hv;
    }
    if (thr < TPB) {
        int tokid = tok_lds[thr];
        unsigned int m = 0;
        if (mcode & 1) {          // bf16 (0.0 / 1.0)
            const unsigned short* p = (const unsigned short*)memb + (size_t)tokid * DDOM;
            #pragma unroll
            for (int d = 0; d < DDOM; ++d) m |= (unsigned)(p[d] != 0) << d;
        } else if (mcode & 2) {   // uint8
            const unsigned char* p = memb + (size_t)tokid * DDOM;
            #pragma unroll
            for (int d = 0; d < DDOM; ++d) m |= (unsigned)(p[d] != 0) << d;
        } else {                  // int32
            const int* p = (const int*)memb + (size_t)tokid * DDOM;
            #pragma unroll
            for (int d = 0; d < DDOM; ++d) m |= (unsigned)(p[d] != 0) << d;
        }
        mask_lds[thr] = m;
    }
    __syncthreads();

    // ---- phase 3: build active (token,domain) pair list ----
    for (int c = thr; c < TPB * DDOM; c += NTHREADS) {
        int t = c >> 4, d = c & 15;
        if ((mask_lds[t] >> d) & 1u) {
            int idx = atomicAdd(&npairs, 1);
            pairs[idx] = (unsigned short)c;
        }
    }
    __syncthreads();

    // ---- phase 4: waves process pairs round-robin ----
    const int np = npairs;
    const int k = lane & 31;     // lane role in step1: output k
    const int p = lane >> 5;     // e-half
    for (int pi = wid; pi < np; pi += 4) {
        int c = pairs[pi];
        int t = c >> 4, d = c & 15;
        const float* __restrict__ w1 = W1 + d * (EDIM * DKDIM);
        // step1: u_k = sum_e h[e]*W1[d,e,k]; each half sums 32 e's (chain halved)
        float u = 0.f;
        #pragma unroll
        for (int j4 = 0; j4 < 8; ++j4) {
            float4 hv = ((const float4*)&h_lds[t][p * 32])[j4];   // uniform addr -> LDS broadcast
            int e = p * 32 + j4 * 4;
            u = fmaf(hv.x, w1[(e + 0) * DKDIM + k], u);
            u = fmaf(hv.y, w1[(e + 1) * DKDIM + k], u);
            u = fmaf(hv.z, w1[(e + 2) * DKDIM + k], u);
            u = fmaf(hv.w, w1[(e + 3) * DKDIM + k], u);
        }
        u += __shfl_xor(u, 32, 64);   // combine halves; all lanes hold u_k, k=lane&31

        // gelu exact: u*Phi(u); |u| ~ N(0, 0.0016) -> odd Taylor exact to <1e-8.
        // Guarded erff fallback for the (impossible in practice) |u|>0.35 case.
        float g;
        float au = fabsf(u);
        if (__builtin_expect(__ballot(au > 0.35f) != 0ull, 0)) {
            g = 0.5f * u * (1.f + erff(u * 0.70710678118654752f));
        } else {
            float u2 = u * u;
            g = u * (0.5f + u * (0.3989422804f + u2 * (-0.06649038f + u2 * 0.00997356f)));
        }

        // step2: corr_e += sum_k g_k * W2[d,k,e]; lane role: e
        const float* __restrict__ w2 = W2 + d * (DKDIM * EDIM);
        float cp = 0.f;
        #pragma unroll
        for (int kk = 0; kk < DKDIM; ++kk) {
            cp = fmaf(__shfl(g, kk, 64), w2[kk * EDIM + lane], cp);  // const-lane -> readlane
        }
        atomicAdd(&corr[t][lane], cp);   // ds_add_f32; cross-wave same-token safe
    }
    __syncthreads();

    // ---- epilogue: out = h + 0.1*corr (coalesced float4) ----
    #pragma unroll
    for (int pass = 0; pass < 2; ++pass) {
        int row = pass * 16 + (thr >> 4);
        int gt = tok0 + row;
        if (gt < ntok) {
            float4 hv = ((const float4*)&h_lds[row][0])[thr & 15];
            float4 cv = ((const float4*)&corr[row][0])[thr & 15];
            float4 o;
            o.x = hv.x + 0.1f * cv.x;
            o.y = hv.y + 0.1f * cv.y;
            o.z = hv.z + 0.1f * cv.z;
            o.w = hv.w + 0.1f * cv.w;
            ((float4*)(out + (size_t)gt * EDIM))[thr & 15] = o;
        }
    }
}

extern "C" void kernel_launch(void* const* d_in, const int* in_sizes, int n_in,
                              void* d_out, int out_size, void* d_ws, size_t ws_size,
                              hipStream_t stream) {
    const int*   x    = (const int*)  d_in[0];
    const float* tab  = (const float*)d_in[1];
    const float* W1   = (const float*)d_in[2];
    const float* W2   = (const float*)d_in[3];
    const unsigned char* memb = (const unsigned char*)d_in[4];
    float* out = (float*)d_out;

    const int ntok = in_sizes[0];                 // B*S = 65536
    const int blocks = (ntok + TPB - 1) / TPB;    // 2048

    domain_embed_fused<<<blocks, NTHREADS, 0, stream>>>(x, tab, W1, W2, memb, out, ntok);
}